// Round 1
// baseline (343.826 us; speedup 1.0000x reference)
//
#include <hip/hip_runtime.h>

#define N3   (64*64*64)      // 262144
#define NO   70
#define NO3  (NO*NO*NO)      // 343000
#define OH   (2*NO3)         // 686000  (h output elements)
#define SZ   (2*16*N3)       // 8388608 (each [B,16,D,H,W] output)

__device__ __forceinline__ float relu(float x){ return x > 0.f ? x : 0.f; }

__global__ __launch_bounds__(256) void ham_fused(
    const float* __restrict__ p, const float* __restrict__ q,
    const float* __restrict__ W1, const float* __restrict__ b1,
    const float* __restrict__ W2, const float* __restrict__ b2,
    const float* __restrict__ W3, const float* __restrict__ b3p,
    float* __restrict__ out)
{
    // ---- stage folded weights into LDS (uniform-broadcast reads later) ----
    __shared__ float WpT[16][16];   // W1[:,0:16]  transposed -> [c][o]
    __shared__ float WqT[16][16];   // W1[:,48:64] transposed -> [c][o]
    __shared__ float W2l[16][16];   // W2[o][c]
    __shared__ float b1l[16], b2l[16], W3l[16];
    __shared__ float s1x[16], s1y[16], s2x[16], s2y[16]; // W1 column-group sums

    int t = threadIdx.x;
    {
        int o = t >> 4, c = t & 15;
        WpT[c][o] = W1[o*96 + c];
        WqT[c][o] = W1[o*96 + 48 + c];
        W2l[o][c] = W2[o*16 + c];
    }
    if (t < 16) {
        b1l[t] = b1[t]; b2l[t] = b2[t]; W3l[t] = W3[t];
        float ax=0.f, ay=0.f, bx=0.f, by=0.f;
        #pragma unroll
        for (int j = 0; j < 16; ++j) {
            ax += W1[t*96 + 16 + j];
            ay += W1[t*96 + 32 + j];
            bx += W1[t*96 + 64 + j];
            by += W1[t*96 + 80 + j];
        }
        s1x[t]=ax; s1y[t]=ay; s2x[t]=bx; s2y[t]=by;
    }
    __syncthreads();

    int idx = blockIdx.x * 256 + t;
    if (idx >= OH) return;

    int b = idx / NO3;
    int r = idx - b*NO3;
    int d = r / (NO*NO); r -= d*(NO*NO);
    int h = r / NO;
    int w = r - h*NO;

    float b3v = b3p[0];
    float outv;

    // Layer-3 source position (y2 space, [0,68)). Out of range -> padding 0.
    if ((unsigned)(d-1) >= 68u || (unsigned)(h-1) >= 68u || (unsigned)(w-1) >= 68u) {
        outv = relu(b3v);
    } else {
        float y2[16];
        // Layer-2 source (y1 space, [0,66))
        if ((unsigned)(d-2) >= 66u || (unsigned)(h-2) >= 66u || (unsigned)(w-2) >= 66u) {
            #pragma unroll
            for (int o = 0; o < 16; ++o) y2[o] = relu(b2l[o]);
        } else {
            float y1[16];
            int d0 = d-3, h0 = h-3, w0 = w-3;
            bool interior = (unsigned)d0 < 64u && (unsigned)h0 < 64u && (unsigned)w0 < 64u;
            if (!interior) {
                #pragma unroll
                for (int c = 0; c < 16; ++c) y1[c] = relu(b1l[c]);
            } else {
                // ---- image gradients from channel 1 (zero-padded) ----
                const float* ps = p + (b*16 + 1)*N3;
                const float* qs = q + (b*16 + 1)*N3;
                auto ld = [&](const float* s, int dd, int hh, int ww) -> float {
                    if ((unsigned)dd >= 64u || (unsigned)hh >= 64u || (unsigned)ww >= 64u)
                        return 0.f;
                    return s[dd*4096 + hh*64 + ww];
                };
                auto g = [&](const float* s, int dd, int hh, int ww) -> float {
                    return 0.5f*(ld(s, dd, hh, ww+1) - ld(s, dd, hh, ww-1));
                };
                float gcp = g(ps, d0, h0, w0);
                float dpx = g(ps, d0-1, h0, w0) + gcp + g(ps, d0+1, h0, w0);
                float dpy = g(ps, d0, h0-1, w0) + gcp + g(ps, d0, h0+1, w0);
                float gcq = g(qs, d0, h0, w0);
                float dqx = g(qs, d0-1, h0, w0) + gcq + g(qs, d0+1, h0, w0);
                float dqy = g(qs, d0, h0-1, w0) + gcq + g(qs, d0, h0+1, w0);

                #pragma unroll
                for (int o = 0; o < 16; ++o)
                    y1[o] = b1l[o] + s1x[o]*dpx + s1y[o]*dpy + s2x[o]*dqx + s2y[o]*dqy;

                int sbase = d0*4096 + h0*64 + w0;
                int ibase = b*16*N3 + sbase;

                float* outp  = out + OH;
                float* outdx = out + OH + SZ;
                float* outdy = out + OH + 2*SZ;
                float* outq  = out + OH + 3*SZ;
                float* outqx = out + OH + 4*SZ;
                float* outqy = out + OH + 5*SZ;

                #pragma unroll
                for (int c = 0; c < 16; ++c) {
                    float pc = p[ibase + c*N3];
                    float qc = q[ibase + c*N3];
                    outp[ibase + c*N3] = pc;   // p passthrough output
                    outq[ibase + c*N3] = qc;   // q passthrough output
                    #pragma unroll
                    for (int o = 0; o < 16; ++o)
                        y1[o] += WpT[c][o]*pc + WqT[c][o]*qc;
                }
                #pragma unroll
                for (int c = 0; c < 16; ++c) {
                    outdx[ibase + c*N3] = dpx; // channel-broadcast gradient outputs
                    outdy[ibase + c*N3] = dpy;
                    outqx[ibase + c*N3] = dqx;
                    outqy[ibase + c*N3] = dqy;
                }
                #pragma unroll
                for (int o = 0; o < 16; ++o) y1[o] = relu(y1[o]);
            }
            #pragma unroll
            for (int o = 0; o < 16; ++o) {
                float a = b2l[o];
                #pragma unroll
                for (int c = 0; c < 16; ++c) a += W2l[o][c]*y1[c];
                y2[o] = relu(a);
            }
        }
        float a = b3v;
        #pragma unroll
        for (int c = 0; c < 16; ++c) a += W3l[c]*y2[c];
        outv = relu(a);
    }
    out[idx] = outv;   // h output, [B,1,70,70,70] flat
}

extern "C" void kernel_launch(void* const* d_in, const int* in_sizes, int n_in,
                              void* d_out, int out_size, void* d_ws, size_t ws_size,
                              hipStream_t stream) {
    const float* p  = (const float*)d_in[0];
    const float* q  = (const float*)d_in[1];
    const float* W1 = (const float*)d_in[2];
    const float* b1 = (const float*)d_in[3];
    const float* W2 = (const float*)d_in[4];
    const float* b2 = (const float*)d_in[5];
    const float* W3 = (const float*)d_in[6];
    const float* b3 = (const float*)d_in[7];
    float* out = (float*)d_out;

    int total = OH;                          // 686000 voxels of h
    int blocks = (total + 255) / 256;        // 2680
    ham_fused<<<blocks, 256, 0, stream>>>(p, q, W1, b1, W2, b2, W3, b3, out);
}